// Round 8
// baseline (570.035 us; speedup 1.0000x reference)
//
#include <hip/hip_runtime.h>

typedef __attribute__((ext_vector_type(8))) short bf16x8;
typedef __attribute__((ext_vector_type(4))) float f32x4;

// RNE float -> bf16
__device__ __forceinline__ unsigned short f2bf(float f) {
    union { float f; unsigned int u; } v; v.f = f;
    unsigned int r = v.u + 0x7FFFu + ((v.u >> 16) & 1u);
    return (unsigned short)(r >> 16);
}

// one TCC atomic op adds 2 bf16 values at p (4B-aligned)
__device__ __forceinline__ void atomic_pk_bf16(unsigned short* p, float lo, float hi) {
    unsigned v;
    asm("v_cvt_pk_bf16_f32 %0, %1, %2" : "=v"(v) : "v"(lo), "v"(hi));
    asm volatile("global_atomic_pk_add_bf16 %0, %1, off" :: "v"(p), "v"(v) : "memory");
}

__global__ void zero_k(unsigned* __restrict__ p, long long nw) {
    long long i = ((long long)blockIdx.x * blockDim.x + threadIdx.x) * 4;
    const long long st = (long long)gridDim.x * blockDim.x * 4;
    for (; i + 4 <= nw; i += st) *(uint4*)(p + i) = make_uint4(0, 0, 0, 0);
    for (; i < nw; ++i) p[i] = 0u;
}

// ---------- G = H @ Wh^T + Mb (no relu), swapped-operand MFMA, K=64 ----------
// Wh = M_W[:, :64] (row stride 128). Lane (kc,lrow) of wave w ends up holding
// features f*16 + kc*4 + {0..3} of row (w*16 + lrow): coalesced f32x4 stores.
__global__ __launch_bounds__(256)
void gemm_g(const float* __restrict__ H, const float* __restrict__ MW,
            const float* __restrict__ Mb, float* __restrict__ G, int rows)
{
    __shared__ char Ab[64 * 128];   // bf16 [64][64], XOR-swizzled
    const int t = threadIdx.x, wave = t >> 6, lane = t & 63;
    const int lrow = lane & 15, kc = lane >> 4, lko = kc * 8, fo = kc * 4;

    bf16x8 wfrag[4][2];
#pragma unroll
    for (int f = 0; f < 4; ++f)
#pragma unroll
        for (int ks = 0; ks < 2; ++ks) {
            const float* wp = MW + (f * 16 + lrow) * 128 + ks * 32 + lko;
            bf16x8 v;
#pragma unroll
            for (int i = 0; i < 8; ++i) ((unsigned short*)&v)[i] = f2bf(wp[i]);
            wfrag[f][ks] = v;
        }
    f32x4 bia[4];
#pragma unroll
    for (int f = 0; f < 4; ++f) bia[f] = *(const f32x4*)(Mb + f * 16 + fo);

    const int el = t >> 2, q = t & 3;
    const int tiles = (rows + 63) >> 6;
    for (int tile = blockIdx.x; tile < tiles; tile += gridDim.x) {
        __syncthreads();
        {
            const long long e = (long long)tile * 64 + el;
            const bool ok = e < (long long)rows;
            const float* ap = H + e * 64;
#pragma unroll
            for (int i = 0; i < 4; ++i) {
                const int c = q * 4 + i;    // 16 chunks of 4 floats per row
                float4 v = make_float4(0.f, 0.f, 0.f, 0.f);
                if (ok) v = *(const float4*)(ap + c * 4);
                unsigned lo32 = (unsigned)f2bf(v.x) | ((unsigned)f2bf(v.y) << 16);
                unsigned hi32 = (unsigned)f2bf(v.z) | ((unsigned)f2bf(v.w) << 16);
                *(uint2*)(Ab + el * 128 + ((c * 8) ^ ((el & 7) << 4))) = make_uint2(lo32, hi32);
            }
        }
        __syncthreads();

        f32x4 acc[4] = {{0,0,0,0},{0,0,0,0},{0,0,0,0},{0,0,0,0}};
        const int drow = wave * 16 + lrow;
#pragma unroll
        for (int ks = 0; ks < 2; ++ks) {
            bf16x8 a = *(const bf16x8*)(Ab + drow * 128 + ((ks * 64 + kc * 16) ^ ((drow & 7) << 4)));
#pragma unroll
            for (int f = 0; f < 4; ++f)
                acc[f] = __builtin_amdgcn_mfma_f32_16x16x32_bf16(wfrag[f][ks], a, acc[f], 0, 0, 0);
        }

        const long long e = (long long)tile * 64 + wave * 16 + lrow;
        if (e < (long long)rows) {
            float* gp = G + e * 64 + fo;
#pragma unroll
            for (int f = 0; f < 4; ++f)
                *(f32x4*)(gp + f * 16) = acc[f] + bia[f];
        }
    }
}

// ---------- edge pass: relu(G[src] + Xe@Wx^T) scattered via pk-bf16 atomics ----------
// Wx = M_W[:, 64:]. Xe tiles are contiguous (natural order) -> coalesced staging.
// G gather: 4 lanes (kc) read one contiguous 64B line of the L2-hot G row.
__global__ __launch_bounds__(256)
void edge_atomic(const float* __restrict__ Xe,
                 const int* __restrict__ src, const int* __restrict__ dst,
                 const float* __restrict__ MW, const float* __restrict__ G,
                 unsigned short* __restrict__ Zb, int E)
{
    __shared__ char Ab[64 * 128];   // bf16 [64][64], XOR-swizzled
    const int t = threadIdx.x, wave = t >> 6, lane = t & 63;
    const int lrow = lane & 15, kc = lane >> 4, lko = kc * 8, fo = kc * 4;

    bf16x8 wfrag[4][2];
#pragma unroll
    for (int f = 0; f < 4; ++f)
#pragma unroll
        for (int ks = 0; ks < 2; ++ks) {
            const float* wp = MW + (f * 16 + lrow) * 128 + 64 + ks * 32 + lko;
            bf16x8 v;
#pragma unroll
            for (int i = 0; i < 8; ++i) ((unsigned short*)&v)[i] = f2bf(wp[i]);
            wfrag[f][ks] = v;
        }

    const int el = t >> 2, q = t & 3;
    const int tiles = (E + 63) >> 6;
    for (int tile = blockIdx.x; tile < tiles; tile += gridDim.x) {
        __syncthreads();
        {
            const long long e = (long long)tile * 64 + el;
            const bool ok = e < (long long)E;
            const float* ap = Xe + e * 64;
#pragma unroll
            for (int i = 0; i < 4; ++i) {
                const int c = q * 4 + i;
                float4 v = make_float4(0.f, 0.f, 0.f, 0.f);
                if (ok) v = *(const float4*)(ap + c * 4);
                unsigned lo32 = (unsigned)f2bf(v.x) | ((unsigned)f2bf(v.y) << 16);
                unsigned hi32 = (unsigned)f2bf(v.z) | ((unsigned)f2bf(v.w) << 16);
                *(uint2*)(Ab + el * 128 + ((c * 8) ^ ((el & 7) << 4))) = make_uint2(lo32, hi32);
            }
        }
        __syncthreads();

        f32x4 acc[4] = {{0,0,0,0},{0,0,0,0},{0,0,0,0},{0,0,0,0}};
        const int drow = wave * 16 + lrow;
#pragma unroll
        for (int ks = 0; ks < 2; ++ks) {
            bf16x8 a = *(const bf16x8*)(Ab + drow * 128 + ((ks * 64 + kc * 16) ^ ((drow & 7) << 4)));
#pragma unroll
            for (int f = 0; f < 4; ++f)
                acc[f] = __builtin_amdgcn_mfma_f32_16x16x32_bf16(wfrag[f][ks], a, acc[f], 0, 0, 0);
        }

        const long long e = (long long)tile * 64 + wave * 16 + lrow;
        if (e < (long long)E) {
            const int s = src[e];
            const int d = dst[e];
            const float* gp = G + (long long)s * 64 + fo;
            unsigned short* zp = Zb + (long long)d * 64 + fo;
#pragma unroll
            for (int f = 0; f < 4; ++f) {
                const f32x4 gv = *(const f32x4*)(gp + f * 16);
                const float y0 = fmaxf(acc[f][0] + gv[0], 0.f);
                const float y1 = fmaxf(acc[f][1] + gv[1], 0.f);
                const float y2 = fmaxf(acc[f][2] + gv[2], 0.f);
                const float y3 = fmaxf(acc[f][3] + gv[3], 0.f);
                atomic_pk_bf16(zp + f * 16 + 0, y0, y1);
                atomic_pk_bf16(zp + f * 16 + 2, y2, y3);
            }
        }
    }
}

// ---------- node pass: H_next = relu([H | Z] @ U_W^T + U_b), Z is bf16 ----------
__global__ __launch_bounds__(256)
void node_mlp(const float* __restrict__ H, const unsigned short* __restrict__ Zb,
              const float* __restrict__ W, const float* __restrict__ bias,
              float* __restrict__ out, int rows)
{
    __shared__ char Ab[64 * 128 * 2];   // bf16 [64][128], XOR-swizzled
    const int t = threadIdx.x, wave = t >> 6, lane = t & 63;
    const int lrow = lane & 15, lko = (lane >> 4) * 8, lko2 = lko * 2;

    bf16x8 bfrag[4][4];
#pragma unroll
    for (int f = 0; f < 4; ++f)
#pragma unroll
        for (int ks = 0; ks < 4; ++ks) {
            const float* wp = W + (f * 16 + lrow) * 128 + ks * 32 + lko;
            bf16x8 v;
#pragma unroll
            for (int i = 0; i < 8; ++i) ((unsigned short*)&v)[i] = f2bf(wp[i]);
            bfrag[f][ks] = v;
        }
    float bia[4];
#pragma unroll
    for (int f = 0; f < 4; ++f) bia[f] = bias[f * 16 + lrow];

    const int el = t >> 2, q = t & 3, swz_w = (el & 7) << 4;
    const int tiles = (rows + 63) >> 6;
    for (int tile = blockIdx.x; tile < tiles; tile += gridDim.x) {
        __syncthreads();
        {
            const long long e = (long long)tile * 64 + el;
            const bool ok = e < (long long)rows;
            const float* ap = H + e * 64;
            const unsigned short* zp = Zb + e * 64;
#pragma unroll
            for (int i = 0; i < 8; ++i) {
                const int c = q + 4 * i;    // chunk 0..31, 4 elements each
                uint2 w2 = make_uint2(0u, 0u);
                if (ok) {
                    if (c < 16) {
                        float4 v = *(const float4*)(ap + c * 4);
                        w2.x = (unsigned)f2bf(v.x) | ((unsigned)f2bf(v.y) << 16);
                        w2.y = (unsigned)f2bf(v.z) | ((unsigned)f2bf(v.w) << 16);
                    } else {
                        w2 = *(const uint2*)(zp + (c - 16) * 4);   // already bf16
                    }
                }
                *(uint2*)(Ab + ((el * 256 + c * 8) ^ swz_w)) = w2;
            }
        }
        __syncthreads();

        f32x4 acc[4] = {{0,0,0,0},{0,0,0,0},{0,0,0,0},{0,0,0,0}};
        const int arl = wave * 16 + lrow, rbase = arl * 256, swz_r = (arl & 7) << 4;
#pragma unroll
        for (int ks = 0; ks < 4; ++ks) {
            bf16x8 a = *(const bf16x8*)(Ab + ((rbase + ks * 64 + lko2) ^ swz_r));
#pragma unroll
            for (int f = 0; f < 4; ++f)
                acc[f] = __builtin_amdgcn_mfma_f32_16x16x32_bf16(a, bfrag[f][ks], acc[f], 0, 0, 0);
        }

        const long long erow0 = (long long)tile * 64 + wave * 16 + (lane >> 4) * 4;
#pragma unroll
        for (int r = 0; r < 4; ++r) {
            const long long e = erow0 + r;
            if (e < (long long)rows) {
                const long long o = e * 64;
#pragma unroll
                for (int f = 0; f < 4; ++f)
                    out[o + f * 16 + lrow] = fmaxf(acc[f][r] + bia[f], 0.f);
            }
        }
    }
}

extern "C" void kernel_launch(void* const* d_in, const int* in_sizes, int n_in,
                              void* d_out, int out_size, void* d_ws, size_t ws_size,
                              hipStream_t stream)
{
    const float* H   = (const float*)d_in[0];
    const float* Xe  = (const float*)d_in[1];
    const int*   idx = (const int*)d_in[2];
    const float* M_W = (const float*)d_in[3];
    const float* M_b = (const float*)d_in[4];
    const float* U_W = (const float*)d_in[5];
    const float* U_b = (const float*)d_in[6];
    float* Hn = (float*)d_out;

    const int n_nodes = out_size / 64;
    const int n_edges = in_sizes[1] / 64;
    const int* src = idx;
    const int* dst = idx + n_edges;

    char* ws = (char*)d_ws;
    float* G = (float*)ws;                                    // [N,64] fp32
    unsigned short* Zb = (unsigned short*)(ws + (size_t)n_nodes * 64 * 4);  // [N,64] bf16

    // zero Z (bf16) only; G is fully overwritten
    zero_k<<<1024, 256, 0, stream>>>((unsigned*)Zb, (long long)n_nodes * 32);

    const int ntiles = (n_nodes + 63) / 64;
    gemm_g<<<ntiles, 256, 0, stream>>>(H, M_W, M_b, G, n_nodes);

    edge_atomic<<<2048, 256, 0, stream>>>(Xe, src, dst, M_W, G, Zb, n_edges);

    node_mlp<<<ntiles, 256, 0, stream>>>(H, Zb, U_W, U_b, Hn, n_nodes);
}

// Round 9
// 550.431 us; speedup vs baseline: 1.0356x; 1.0356x over previous
//
#include <hip/hip_runtime.h>

typedef __attribute__((ext_vector_type(8))) short bf16x8;
typedef __attribute__((ext_vector_type(4))) float f32x4;

// RNE float -> bf16
__device__ __forceinline__ unsigned short f2bf(float f) {
    union { float f; unsigned int u; } v; v.f = f;
    unsigned int r = v.u + 0x7FFFu + ((v.u >> 16) & 1u);
    return (unsigned short)(r >> 16);
}
__device__ __forceinline__ float bf2f(unsigned short h) {
    union { unsigned int u; float f; } v; v.u = (unsigned int)h << 16;
    return v.f;
}

__global__ void zero_k(unsigned* __restrict__ p, long long nw) {
    long long i = ((long long)blockIdx.x * blockDim.x + threadIdx.x) * 4;
    const long long st = (long long)gridDim.x * blockDim.x * 4;
    for (; i + 4 <= nw; i += st) *(uint4*)(p + i) = make_uint4(0, 0, 0, 0);
    for (; i < nw; ++i) p[i] = 0u;
}

// ---------------- sort chain: hist -> 3-kernel scan -> eord scatter ----------------
__global__ void hist_k(const int* __restrict__ dst, unsigned* __restrict__ counts, int E) {
    for (int i = blockIdx.x * blockDim.x + threadIdx.x; i < E; i += gridDim.x * blockDim.x)
        atomicAdd(&counts[dst[i]], 1u);
}

__global__ __launch_bounds__(256)
void scan_a(const unsigned* __restrict__ counts, unsigned* __restrict__ bsum, int N) {
    __shared__ unsigned s[256];
    const int i = blockIdx.x * 256 + threadIdx.x;
    s[threadIdx.x] = (i < N) ? counts[i] : 0u;
    __syncthreads();
    for (int o = 128; o > 0; o >>= 1) {
        if (threadIdx.x < o) s[threadIdx.x] += s[threadIdx.x + o];
        __syncthreads();
    }
    if (!threadIdx.x) bsum[blockIdx.x] = s[0];
}

__global__ __launch_bounds__(256)
void scan_b(const unsigned* __restrict__ bsum, unsigned* __restrict__ boff, int nb) {
    __shared__ unsigned part[256];
    const int t = threadIdx.x;
    const int chunk = (nb + 255) >> 8;
    const int lo = t * chunk, hi = min(lo + chunk, nb);
    unsigned s = 0;
    for (int i = lo; i < hi; ++i) s += bsum[i];
    part[t] = s;
    __syncthreads();
    for (int o = 1; o < 256; o <<= 1) {
        unsigned v = (t >= o) ? part[t - o] : 0u;
        __syncthreads();
        part[t] += v;
        __syncthreads();
    }
    unsigned run = t ? part[t - 1] : 0u;
    for (int i = lo; i < hi; ++i) { boff[i] = run; run += bsum[i]; }
}

__global__ __launch_bounds__(256)
void scan_c(const unsigned* __restrict__ counts, const unsigned* __restrict__ boff,
            unsigned* __restrict__ cursor, int N) {
    __shared__ unsigned part[256];
    const int t = threadIdx.x;
    const int i = blockIdx.x * 256 + t;
    const unsigned v = (i < N) ? counts[i] : 0u;
    part[t] = v;
    __syncthreads();
    for (int o = 1; o < 256; o <<= 1) {
        unsigned u = (t >= o) ? part[t - o] : 0u;
        __syncthreads();
        part[t] += u;
        __syncthreads();
    }
    if (i < N) cursor[i] = boff[blockIdx.x] + part[t] - v;   // exclusive prefix
}

// eord[p] = original edge id at sorted position p (4B random writes, L2-absorbed)
__global__ void scatter_k(const int* __restrict__ dst, unsigned* __restrict__ cursor,
                          unsigned* __restrict__ eord, int E) {
    for (int i = blockIdx.x * blockDim.x + threadIdx.x; i < E; i += gridDim.x * blockDim.x)
        eord[atomicAdd(&cursor[dst[i]], 1u)] = (unsigned)i;
}

// ---------- G = bf16(H @ Wh^T + Mb), Wh = M_W[:, :64] ----------
__global__ __launch_bounds__(256)
void gemm_g(const float* __restrict__ H, const float* __restrict__ MW,
            const float* __restrict__ Mb, unsigned short* __restrict__ Gb, int rows)
{
    __shared__ char Ab[64 * 128];   // bf16 [64][64], XOR-swizzled
    const int t = threadIdx.x, wave = t >> 6, lane = t & 63;
    const int lrow = lane & 15, kc = lane >> 4, lko = kc * 8, fo = kc * 4;

    bf16x8 wfrag[4][2];
#pragma unroll
    for (int f = 0; f < 4; ++f)
#pragma unroll
        for (int ks = 0; ks < 2; ++ks) {
            const float* wp = MW + (f * 16 + lrow) * 128 + ks * 32 + lko;
            bf16x8 v;
#pragma unroll
            for (int i = 0; i < 8; ++i) ((unsigned short*)&v)[i] = f2bf(wp[i]);
            wfrag[f][ks] = v;
        }
    f32x4 bia[4];
#pragma unroll
    for (int f = 0; f < 4; ++f) bia[f] = *(const f32x4*)(Mb + f * 16 + fo);

    const int el = t >> 2, q = t & 3;
    const int tiles = (rows + 63) >> 6;
    for (int tile = blockIdx.x; tile < tiles; tile += gridDim.x) {
        __syncthreads();
        {
            const long long e = (long long)tile * 64 + el;
            const bool ok = e < (long long)rows;
            const float* ap = H + e * 64;
#pragma unroll
            for (int i = 0; i < 4; ++i) {
                const int c = q * 4 + i;
                float4 v = make_float4(0.f, 0.f, 0.f, 0.f);
                if (ok) v = *(const float4*)(ap + c * 4);
                unsigned lo32 = (unsigned)f2bf(v.x) | ((unsigned)f2bf(v.y) << 16);
                unsigned hi32 = (unsigned)f2bf(v.z) | ((unsigned)f2bf(v.w) << 16);
                *(uint2*)(Ab + el * 128 + ((c * 8) ^ ((el & 7) << 4))) = make_uint2(lo32, hi32);
            }
        }
        __syncthreads();

        f32x4 acc[4] = {{0,0,0,0},{0,0,0,0},{0,0,0,0},{0,0,0,0}};
        const int drow = wave * 16 + lrow;
#pragma unroll
        for (int ks = 0; ks < 2; ++ks) {
            bf16x8 a = *(const bf16x8*)(Ab + drow * 128 + ((ks * 64 + kc * 16) ^ ((drow & 7) << 4)));
#pragma unroll
            for (int f = 0; f < 4; ++f)
                acc[f] = __builtin_amdgcn_mfma_f32_16x16x32_bf16(wfrag[f][ks], a, acc[f], 0, 0, 0);
        }

        const long long e = (long long)tile * 64 + wave * 16 + lrow;
        if (e < (long long)rows) {
            unsigned short* gp = Gb + e * 64 + fo;
#pragma unroll
            for (int f = 0; f < 4; ++f) {
                const f32x4 o = acc[f] + bia[f];
                ushort4 y;
                y.x = f2bf(o[0]); y.y = f2bf(o[1]); y.z = f2bf(o[2]); y.w = f2bf(o[3]);
                *(ushort4*)(gp + f * 16) = y;
            }
        }
    }
}

// ---------- X~ = bf16(Xe @ Wx^T), natural order, pure streaming ----------
// One wave = 16 consecutive edges; no LDS, no barriers, no bias, no relu.
__global__ __launch_bounds__(256, 4)
void edge_xw(const float* __restrict__ Xe, const float* __restrict__ MW,
             unsigned short* __restrict__ Xb, int E)
{
    const int t = threadIdx.x, lane = t & 63;
    const int lrow = lane & 15, kc = lane >> 4, lko = kc * 8, fo = kc * 4;
    const long long gw = ((long long)blockIdx.x * blockDim.x + t) >> 6;
    const long long nw = ((long long)gridDim.x * blockDim.x) >> 6;
    const long long ngrp = ((long long)E + 15) >> 4;

    // Wx fragments (A-operand): lane holds M_W[f*16+lrow][64 + ks*32 + lko + i]
    bf16x8 wfrag[4][2];
#pragma unroll
    for (int f = 0; f < 4; ++f)
#pragma unroll
        for (int ks = 0; ks < 2; ++ks) {
            const float* wp = MW + (f * 16 + lrow) * 128 + 64 + ks * 32 + lko;
            bf16x8 v;
#pragma unroll
            for (int i = 0; i < 8; ++i) ((unsigned short*)&v)[i] = f2bf(wp[i]);
            wfrag[f][ks] = v;
        }

    for (long long g = gw; g < ngrp; g += nw) {
        const long long e = g * 16 + lrow;
        const bool ok = e < (long long)E;
        const float* xp = Xe + e * 64;

        bf16x8 dfrag[2];
#pragma unroll
        for (int ks = 0; ks < 2; ++ks) {
            float4 a = make_float4(0.f, 0.f, 0.f, 0.f), b = a;
            if (ok) {
                a = *(const float4*)(xp + ks * 32 + lko);
                b = *(const float4*)(xp + ks * 32 + lko + 4);
            }
            bf16x8 v;
            ((unsigned short*)&v)[0] = f2bf(a.x); ((unsigned short*)&v)[1] = f2bf(a.y);
            ((unsigned short*)&v)[2] = f2bf(a.z); ((unsigned short*)&v)[3] = f2bf(a.w);
            ((unsigned short*)&v)[4] = f2bf(b.x); ((unsigned short*)&v)[5] = f2bf(b.y);
            ((unsigned short*)&v)[6] = f2bf(b.z); ((unsigned short*)&v)[7] = f2bf(b.w);
            dfrag[ks] = v;
        }

        f32x4 acc[4] = {{0,0,0,0},{0,0,0,0},{0,0,0,0},{0,0,0,0}};
#pragma unroll
        for (int ks = 0; ks < 2; ++ks)
#pragma unroll
            for (int f = 0; f < 4; ++f)
                acc[f] = __builtin_amdgcn_mfma_f32_16x16x32_bf16(wfrag[f][ks], dfrag[ks], acc[f], 0, 0, 0);

        if (ok) {
            unsigned short* op = Xb + e * 64 + fo;
#pragma unroll
            for (int f = 0; f < 4; ++f) {
                ushort4 y;
                y.x = f2bf(acc[f][0]); y.y = f2bf(acc[f][1]);
                y.z = f2bf(acc[f][2]); y.w = f2bf(acc[f][3]);
                *(ushort4*)(op + f * 16) = y;
            }
        }
    }
}

// ---------- Z[n] = sum over edges of relu(G[src] + X~[e]); wave per node ----------
__global__ __launch_bounds__(256)
void seg_k(const unsigned short* __restrict__ Xb, const unsigned short* __restrict__ Gb,
           const int* __restrict__ src, const unsigned* __restrict__ eord,
           const unsigned* __restrict__ counts, const unsigned* __restrict__ cursor,
           float* __restrict__ Z, int N)
{
    const int lane = threadIdx.x & 63;
    const int n = (blockIdx.x * blockDim.x + threadIdx.x) >> 6;
    if (n >= N) return;
    const unsigned e = cursor[n];
    const unsigned b = e - counts[n];
    float acc = 0.f;
    unsigned eo0 = (b < e) ? eord[b] : 0u;
    int s0 = (b < e) ? src[eo0] : 0;
    for (unsigned p = b; p < e; ++p) {
        const unsigned eo1 = (p + 1 < e) ? eord[p + 1] : 0u;   // prefetch next
        const int s1 = (p + 1 < e) ? src[eo1] : 0;
        const float x = bf2f(Xb[(long long)eo0 * 64 + lane]);
        const float g = bf2f(Gb[(long long)s0 * 64 + lane]);
        acc += fmaxf(x + g, 0.f);
        eo0 = eo1; s0 = s1;
    }
    Z[(long long)n * 64 + lane] = acc;
}

// ------------- generic tiled MLP (R1, known-good): node pass + fallback -------------
__global__ __launch_bounds__(256)
void gnn_mlp(const float* __restrict__ A, const float* __restrict__ B2,
             const int* __restrict__ gidx, const int* __restrict__ sidx,
             const float* __restrict__ W, const float* __restrict__ bias,
             float* __restrict__ out, int rows, int ntiles)
{
    __shared__ char Ab[64 * 128 * 2];
    const int t = threadIdx.x, wave = t >> 6, lane = t & 63;
    const int lrow = lane & 15, lko = (lane >> 4) * 8, lko2 = lko * 2;

    bf16x8 bfrag[4][4];
#pragma unroll
    for (int f = 0; f < 4; ++f)
#pragma unroll
        for (int ks = 0; ks < 4; ++ks) {
            const float* wp = W + (f * 16 + lrow) * 128 + ks * 32 + lko;
            bf16x8 v;
#pragma unroll
            for (int i = 0; i < 8; ++i) ((unsigned short*)&v)[i] = f2bf(wp[i]);
            bfrag[f][ks] = v;
        }
    float bia[4];
#pragma unroll
    for (int f = 0; f < 4; ++f) bia[f] = bias[f * 16 + lrow];

    const int el = t >> 2, q = t & 3, swz_w = (el & 7) << 4;

    for (int tile = blockIdx.x; tile < ntiles; tile += gridDim.x) {
        __syncthreads();
        {
            const long long e = (long long)tile * 64 + el;
            const bool ok = e < (long long)rows;
            long long arow = 0;
            if (ok) arow = gidx ? (long long)gidx[e] : e;
            const float* ap = A  + arow * 64;
            const float* bp = B2 + e * 64;
#pragma unroll
            for (int i = 0; i < 8; ++i) {
                const int c = q + 4 * i;
                float4 v = make_float4(0.f, 0.f, 0.f, 0.f);
                if (ok) v = (c < 16) ? *(const float4*)(ap + c * 4)
                                     : *(const float4*)(bp + (c - 16) * 4);
                unsigned lo32 = (unsigned)f2bf(v.x) | ((unsigned)f2bf(v.y) << 16);
                unsigned hi32 = (unsigned)f2bf(v.z) | ((unsigned)f2bf(v.w) << 16);
                *(uint2*)(Ab + ((el * 256 + c * 8) ^ swz_w)) = make_uint2(lo32, hi32);
            }
        }
        __syncthreads();

        f32x4 acc[4] = {{0,0,0,0},{0,0,0,0},{0,0,0,0},{0,0,0,0}};
        const int arl = wave * 16 + lrow, rbase = arl * 256, swz_r = (arl & 7) << 4;
#pragma unroll
        for (int ks = 0; ks < 4; ++ks) {
            bf16x8 a = *(const bf16x8*)(Ab + ((rbase + ks * 64 + lko2) ^ swz_r));
#pragma unroll
            for (int f = 0; f < 4; ++f)
                acc[f] = __builtin_amdgcn_mfma_f32_16x16x32_bf16(a, bfrag[f][ks], acc[f], 0, 0, 0);
        }

        const long long erow0 = (long long)tile * 64 + wave * 16 + (lane >> 4) * 4;
#pragma unroll
        for (int r = 0; r < 4; ++r) {
            const long long e = erow0 + r;
            if (e < (long long)rows) {
                if (sidx) {
                    const long long d = (long long)sidx[e] * 64;
#pragma unroll
                    for (int f = 0; f < 4; ++f)
                        atomicAdd(out + d + f * 16 + lrow, fmaxf(acc[f][r] + bia[f], 0.f));
                } else {
                    const long long o = e * 64;
#pragma unroll
                    for (int f = 0; f < 4; ++f)
                        out[o + f * 16 + lrow] = fmaxf(acc[f][r] + bia[f], 0.f);
                }
            }
        }
    }
}

extern "C" void kernel_launch(void* const* d_in, const int* in_sizes, int n_in,
                              void* d_out, int out_size, void* d_ws, size_t ws_size,
                              hipStream_t stream)
{
    const float* H   = (const float*)d_in[0];
    const float* Xe  = (const float*)d_in[1];
    const int*   idx = (const int*)d_in[2];
    const float* M_W = (const float*)d_in[3];
    const float* M_b = (const float*)d_in[4];
    const float* U_W = (const float*)d_in[5];
    const float* U_b = (const float*)d_in[6];
    float* Hn = (float*)d_out;

    const int n_nodes = out_size / 64;
    const int n_edges = in_sizes[1] / 64;
    const int* src = idx;
    const int* dst = idx + n_edges;

    char* ws = (char*)d_ws;
    float* Z = (float*)ws;                                  // [N,64] fp32
    size_t off = (size_t)n_nodes * 64 * 4;
    unsigned* counts = (unsigned*)(ws + off); off += (size_t)n_nodes * 4;
    unsigned* cursor = (unsigned*)(ws + off); off += (size_t)n_nodes * 4;
    const int nb = (n_nodes + 255) / 256;
    unsigned* bsum = (unsigned*)(ws + off); off += (size_t)nb * 4;
    unsigned* boff = (unsigned*)(ws + off); off += (size_t)nb * 4;
    unsigned* eord = (unsigned*)(ws + off); off += (size_t)n_edges * 4;
    unsigned short* Gb = (unsigned short*)(ws + off); off += (size_t)n_nodes * 64 * 2;
    unsigned short* Xb = (unsigned short*)(ws + off); off += (size_t)n_edges * 64 * 2;
    const size_t need = off;

    const int ntiles = (n_nodes + 63) / 64;

    if (ws_size >= need) {
        zero_k<<<64, 256, 0, stream>>>(counts, n_nodes);
        hist_k<<<1024, 256, 0, stream>>>(dst, counts, n_edges);
        scan_a<<<nb, 256, 0, stream>>>(counts, bsum, n_nodes);
        scan_b<<<1, 256, 0, stream>>>(bsum, boff, nb);
        scan_c<<<nb, 256, 0, stream>>>(counts, boff, cursor, n_nodes);
        scatter_k<<<1024, 256, 0, stream>>>(dst, cursor, eord, n_edges);
        gemm_g<<<ntiles, 256, 0, stream>>>(H, M_W, M_b, Gb, n_nodes);
        edge_xw<<<4096, 256, 0, stream>>>(Xe, M_W, Xb, n_edges);
        seg_k<<<(n_nodes + 3) / 4, 256, 0, stream>>>(Xb, Gb, src, eord, counts, cursor, Z, n_nodes);
    } else {
        // fallback: R1 atomic path
        zero_k<<<2048, 256, 0, stream>>>((unsigned*)Z, (long long)n_nodes * 64);
        const int etiles = (n_edges + 63) / 64;
        gnn_mlp<<<2048, 256, 0, stream>>>(H, Xe, src, dst, M_W, M_b, Z, n_edges, etiles);
    }

    gnn_mlp<<<ntiles, 256, 0, stream>>>(H, Z, nullptr, nullptr, U_W, U_b, Hn, n_nodes, ntiles);
}